// Round 5
// baseline (1172.666 us; speedup 1.0000x reference)
//
#include <hip/hip_runtime.h>

// ---------------------------------------------------------------------------
// AttentionLayer: q=XWq+bq, k=XWk+bk, v=XWv+bv; S=qk^T (NO 1/sqrt(d) scale);
// P=softmax(S); out=PV.   B=4, L=4096, D=768, fp32 in/out.
//
// Precision: hi/lo _Float16 split (Markidis) for X,W in the PROJECTION GEMMs
// (q,k,v computed accurately); Q,K stored hi-only f16 for the attention
// (R4 dropped K-lo: +0.004 absmax; R5 drops Q-lo: predicted ~+0.005).
// P,V plain f16. All matmuls mfma_f32_16x16x32_f16.
//
// R5: two levers on the validated traffic model (time = L2 traffic / ~14TB/s):
//  - Q hi-only QK^T: per-block-iter traffic 192->144 KB, QK^T MFMA halved.
//  - 8 waves/block @ Q-tile 32 (512 thr, grid 512 = 2 blocks/CU -> 16
//    waves/CU = 4/SIMD, double R4): each wave owns a 96-col d-chunk for
//    both QK^T and PV. Same traffic, 2x latency hiding.
// ---------------------------------------------------------------------------

typedef _Float16 f16;
typedef _Float16 f16x8 __attribute__((ext_vector_type(8)));
typedef _Float16 f16x4 __attribute__((ext_vector_type(4)));
typedef _Float16 f16x2 __attribute__((ext_vector_type(2)));
typedef float f32x4 __attribute__((ext_vector_type(4)));

#define NB 4
#define NL 4096
#define ND 768
#define NM (NB * NL)  // 16384 rows

__device__ __forceinline__ void split_f16(float v, f16& h, f16& l) {
    h = (f16)v;
    l = (f16)(v - (float)h);
}

// ---- convert hidden_states -> Xh, Xl (hi/lo f16), same [M][D] layout ------
__global__ __launch_bounds__(256) void k_convert_x(
    const float* __restrict__ x, f16* __restrict__ xh, f16* __restrict__ xl) {
    int i = blockIdx.x * 256 + threadIdx.x;       // group of 4 elems
    float4 v = ((const float4*)x)[i];
    float vv[4] = {v.x, v.y, v.z, v.w};
    f16x4 hv, lv;
    for (int j = 0; j < 4; ++j) {
        f16 h, l; split_f16(vv[j], h, l);
        hv[j] = h; lv[j] = l;
    }
    ((f16x4*)xh)[i] = hv;
    ((f16x4*)xl)[i] = lv;
}

// ---- transpose W [k][n] -> Wt [n][k] as hi/lo f16 (3 matrices, z picks) ---
__global__ __launch_bounds__(256) void k_convert_w(
    const float* __restrict__ Wq, const float* __restrict__ Wk,
    const float* __restrict__ Wv, f16* __restrict__ wth, f16* __restrict__ wtl) {
    __shared__ float tile[32][33];
    const float* W = blockIdx.z == 0 ? Wq : (blockIdx.z == 1 ? Wk : Wv);
    f16* th = wth + blockIdx.z * ND * ND;
    f16* tl = wtl + blockIdx.z * ND * ND;
    const int k0 = blockIdx.x * 32, n0 = blockIdx.y * 32;
    const int tx = threadIdx.x & 31, ty = threadIdx.x >> 5;  // ty 0..7
    for (int r = 0; r < 4; ++r)
        tile[r * 8 + ty][tx] = W[(k0 + r * 8 + ty) * ND + n0 + tx];
    __syncthreads();
    for (int r = 0; r < 4; ++r) {
        float v = tile[tx][r * 8 + ty];
        int n = n0 + r * 8 + ty, k = k0 + tx;
        f16 h, l; split_f16(v, h, l);
        th[n * ND + k] = h;
        tl[n * ND + k] = l;
    }
}

// ---- projection GEMM: C[M,N] = X[M,K] * W[K,N] + bias, hi/lo MFMA ---------
// z=0 -> Qh (hi only), z=1 -> Kh (hi only), z=2 -> Vt ([b][d][pos], hi)
// 128x128 tile, 4 waves in 2x2, each wave 64x64 = 4x4 frags of 16x16.
__global__ __launch_bounds__(256, 2) void k_proj(
    const f16* __restrict__ xh, const f16* __restrict__ xl,
    const f16* __restrict__ wth, const f16* __restrict__ wtl,
    const float* __restrict__ bq, const float* __restrict__ bk,
    const float* __restrict__ bv,
    f16* __restrict__ qh, f16* __restrict__ kh, f16* __restrict__ vt) {
    const int z = blockIdx.z;
    const f16* wh = wth + z * ND * ND;
    const f16* wl = wtl + z * ND * ND;
    const float* bias = z == 0 ? bq : (z == 1 ? bk : bv);
    const int m0 = blockIdx.x * 128, n0 = blockIdx.y * 128;

    // LDS: rows padded to 40 f16 (80B stride -> only 2-way bank aliasing=free)
    __shared__ f16 Ah[128 * 40], Al[128 * 40], Bh[128 * 40], Bl[128 * 40];

    const int t = threadIdx.x;
    const int lane = t & 63, quad = lane >> 4, l16 = lane & 15;
    const int wave = t >> 6, wm = wave >> 1, wn = wave & 1;

    f32x4 acc[4][4] = {};

    for (int kt = 0; kt < 24; ++kt) {
        const int k0 = kt * 32;
        __syncthreads();
        // stage 128x32 tiles (hi+lo of A and B) via 16B chunks
        for (int i = 0; i < 2; ++i) {
            int c = i * 256 + t;
            int row = c >> 2, kc = (c & 3) * 8;
            *(uint4*)&Ah[row * 40 + kc] = *(const uint4*)&xh[(m0 + row) * ND + k0 + kc];
            *(uint4*)&Al[row * 40 + kc] = *(const uint4*)&xl[(m0 + row) * ND + k0 + kc];
            *(uint4*)&Bh[row * 40 + kc] = *(const uint4*)&wh[(n0 + row) * ND + k0 + kc];
            *(uint4*)&Bl[row * 40 + kc] = *(const uint4*)&wl[(n0 + row) * ND + k0 + kc];
        }
        __syncthreads();
        f16x8 ah[4], al[4], bh[4], bl[4];
#pragma unroll
        for (int f = 0; f < 4; ++f) {
            int m = wm * 64 + f * 16 + l16;
            ah[f] = *(const f16x8*)&Ah[m * 40 + quad * 8];
            al[f] = *(const f16x8*)&Al[m * 40 + quad * 8];
            int n = wn * 64 + f * 16 + l16;
            bh[f] = *(const f16x8*)&Bh[n * 40 + quad * 8];
            bl[f] = *(const f16x8*)&Bl[n * 40 + quad * 8];
        }
#pragma unroll
        for (int fm = 0; fm < 4; ++fm)
#pragma unroll
            for (int fn = 0; fn < 4; ++fn) {
                f32x4 c = acc[fm][fn];
                c = __builtin_amdgcn_mfma_f32_16x16x32_f16(al[fm], bh[fn], c, 0, 0, 0);
                c = __builtin_amdgcn_mfma_f32_16x16x32_f16(ah[fm], bl[fn], c, 0, 0, 0);
                c = __builtin_amdgcn_mfma_f32_16x16x32_f16(ah[fm], bh[fn], c, 0, 0, 0);
                acc[fm][fn] = c;
            }
    }
    // epilogue: C/D layout col=lane&15, row=quad*4+reg  [verified m89/m91]
#pragma unroll
    for (int fm = 0; fm < 4; ++fm)
#pragma unroll
        for (int fn = 0; fn < 4; ++fn) {
            int col = n0 + wn * 64 + fn * 16 + l16;
            float bv_ = bias[col];
#pragma unroll
            for (int r = 0; r < 4; ++r) {
                int row = m0 + wm * 64 + fm * 16 + quad * 4 + r;
                float v = acc[fm][fn][r] + bv_;
                f16 h = (f16)v;
                if (z == 0) { qh[row * ND + col] = h; }
                else if (z == 1) { kh[row * ND + col] = h; }
                else {
                    int b = row >> 12, pos = row & 4095;
                    vt[(b * ND + col) * NL + pos] = h;  // V^T for PV b_frags
                }
            }
        }
}

// ---- flash attention: Q-tile=32 rows/block, 512 threads (8 waves) ---------
// Each wave owns d-chunk [w*96, w*96+96) for BOTH the QK^T partial (3
// k-steps of 32, sacc[2][2]) and the PV output columns (oacc[2][6]).
// Sbuf[8] partials -> 512-thread reduce -> online softmax -> PV.
// Grid (NL/32, NB) = 512 blocks of 512 thr -> 2 blocks/CU, 4 waves/SIMD.
__global__ __launch_bounds__(512, 4) void k_attn(
    const f16* __restrict__ qh, const f16* __restrict__ kh,
    const f16* __restrict__ vt, float* __restrict__ out) {
    const int qt = blockIdx.x, b = blockIdx.y;
    const int q0 = qt * 32;
    const int t = threadIdx.x, w = t >> 6, lane = t & 63;
    const int quad = lane >> 4, l16 = lane & 15;
    const int dw = w * 96;  // this wave's d-chunk (QK^T) and col-chunk (PV)

    __shared__ float Sbuf[8][32][33];  // per-wave partial S (padded)
    __shared__ f16 Pbuf[32 * 40];      // P tile, row stride 40
    __shared__ float mstate[32], lstate[32], abuf[32];

    if (t < 32) { mstate[t] = -1e30f; lstate[t] = 0.f; }
    f32x4 oacc[2][6] = {};  // O acc: 2 row-frags x 6 col-frags (96 cols)
    __syncthreads();

    for (int kt = 0; kt < 128; ++kt) {
        const int p0 = kt * 32;

        // ---- hoist V loads: latency hides under QK^T compute ----
        f16x8 vb[6];
#pragma unroll
        for (int fn = 0; fn < 6; ++fn) {
            const int dcol = dw + fn * 16 + l16;
            vb[fn] = *(const f16x8*)&vt[(b * ND + dcol) * NL + p0 + quad * 8];
        }

        // ---- S partial = Q[q0:+32, dw:+96] * K^T (hi x hi only) ----
        f32x4 sacc[2][2] = {};
#pragma unroll
        for (int dk = 0; dk < 3; ++dk) {
            const int d = dw + dk * 32 + quad * 8;
            f16x8 aH[2], bH[2];
#pragma unroll
            for (int f = 0; f < 2; ++f) {
                aH[f] = *(const f16x8*)&qh[(b * NL + q0 + f * 16 + l16) * ND + d];
                bH[f] = *(const f16x8*)&kh[(b * NL + p0 + f * 16 + l16) * ND + d];
            }
#pragma unroll
            for (int fm = 0; fm < 2; ++fm)
#pragma unroll
                for (int fn = 0; fn < 2; ++fn)
                    sacc[fm][fn] = __builtin_amdgcn_mfma_f32_16x16x32_f16(
                        aH[fm], bH[fn], sacc[fm][fn], 0, 0, 0);
        }
#pragma unroll
        for (int fm = 0; fm < 2; ++fm)
#pragma unroll
            for (int fn = 0; fn < 2; ++fn)
#pragma unroll
                for (int r = 0; r < 4; ++r)
                    Sbuf[w][fm * 16 + quad * 4 + r][fn * 16 + l16] = sacc[fm][fn][r];
        __syncthreads();  // bar1: Sbuf complete

        // ---- online softmax: 512 threads = 32 rows x 16 lanes (2 cols each)
        {
            const int r = t >> 4;          // 0..31
            const int c0 = (t & 15) * 2;   // 0,2,...,30
            float s0 = 0.f, s1 = 0.f;
#pragma unroll
            for (int wv = 0; wv < 8; ++wv) {
                s0 += Sbuf[wv][r][c0];
                s1 += Sbuf[wv][r][c0 + 1];
            }
            float mx = fmaxf(s0, s1);
#pragma unroll
            for (int off = 1; off < 16; off <<= 1) mx = fmaxf(mx, __shfl_xor(mx, off, 64));
            float m_old = mstate[r];
            float m_new = fmaxf(m_old, mx);
            float p0v = __expf(s0 - m_new), p1v = __expf(s1 - m_new);
            float psum = p0v + p1v;
#pragma unroll
            for (int off = 1; off < 16; off <<= 1) psum += __shfl_xor(psum, off, 64);
            float alpha = __expf(m_old - m_new);
            if ((t & 15) == 0) {
                mstate[r] = m_new;
                lstate[r] = alpha * lstate[r] + psum;
                abuf[r] = alpha;
            }
            f16x2 pv2; pv2[0] = (f16)p0v; pv2[1] = (f16)p1v;
            *(f16x2*)&Pbuf[r * 40 + c0] = pv2;
        }
        __syncthreads();  // bar2: Pbuf/abuf complete

        // ---- rescale O by alpha, then O += P * V over this wave's 96 cols --
        float av[2][4];
#pragma unroll
        for (int fm = 0; fm < 2; ++fm)
#pragma unroll
            for (int r = 0; r < 4; ++r) av[fm][r] = abuf[fm * 16 + quad * 4 + r];
#pragma unroll
        for (int fm = 0; fm < 2; ++fm)
#pragma unroll
            for (int fn = 0; fn < 6; ++fn)
#pragma unroll
                for (int r = 0; r < 4; ++r) oacc[fm][fn][r] *= av[fm][r];

        f16x8 pa[2];
#pragma unroll
        for (int fm = 0; fm < 2; ++fm)
            pa[fm] = *(const f16x8*)&Pbuf[(fm * 16 + l16) * 40 + quad * 8];
#pragma unroll
        for (int fn = 0; fn < 6; ++fn)
#pragma unroll
            for (int fm = 0; fm < 2; ++fm)
                oacc[fm][fn] = __builtin_amdgcn_mfma_f32_16x16x32_f16(
                    pa[fm], vb[fn], oacc[fm][fn], 0, 0, 0);
        // no 3rd barrier: next tile's Sbuf writes are ordered after bar2(kt),
        // and Pbuf/abuf rewrites after bar1(kt+1) — both hazard-free.
    }

    // ---- epilogue: out = O / l ----
    float linv[2][4];
#pragma unroll
    for (int fm = 0; fm < 2; ++fm)
#pragma unroll
        for (int r = 0; r < 4; ++r) linv[fm][r] = 1.f / lstate[fm * 16 + quad * 4 + r];
#pragma unroll
    for (int fm = 0; fm < 2; ++fm)
#pragma unroll
        for (int fn = 0; fn < 6; ++fn) {
            int col = dw + fn * 16 + l16;
#pragma unroll
            for (int r = 0; r < 4; ++r) {
                int row = b * NL + q0 + fm * 16 + quad * 4 + r;
                out[row * ND + col] = oacc[fm][fn][r] * linv[fm][r];
            }
        }
}

extern "C" void kernel_launch(void* const* d_in, const int* in_sizes, int n_in,
                              void* d_out, int out_size, void* d_ws, size_t ws_size,
                              hipStream_t stream) {
    const float* hs = (const float*)d_in[0];
    const float* Wq = (const float*)d_in[1];
    const float* bq = (const float*)d_in[2];
    const float* Wk = (const float*)d_in[3];
    const float* bk = (const float*)d_in[4];
    const float* Wv = (const float*)d_in[5];
    const float* bv = (const float*)d_in[6];
    float* out = (float*)d_out;

    char* ws = (char*)d_ws;
    size_t off = 0;
    auto alloc = [&](size_t bytes) {
        void* p = ws + off;
        off += (bytes + 255) & ~(size_t)255;
        return p;
    };
    const size_t MD = (size_t)NM * ND;  // 12,582,912
    f16* Xh = (f16*)alloc(MD * 2);
    f16* Xl = (f16*)alloc(MD * 2);
    f16* Wth = (f16*)alloc((size_t)3 * ND * ND * 2);
    f16* Wtl = (f16*)alloc((size_t)3 * ND * ND * 2);
    f16* Qh = (f16*)alloc(MD * 2);
    f16* Kh = (f16*)alloc(MD * 2);
    f16* Vt = (f16*)alloc(MD * 2);
    (void)ws_size; (void)in_sizes; (void)n_in; (void)out_size;

    k_convert_x<<<dim3(MD / 1024), 256, 0, stream>>>(hs, Xh, Xl);
    k_convert_w<<<dim3(24, 24, 3), 256, 0, stream>>>(Wq, Wk, Wv, Wth, Wtl);
    k_proj<<<dim3(NM / 128, ND / 128, 3), 256, 0, stream>>>(
        Xh, Xl, Wth, Wtl, bq, bk, bv, Qh, Kh, Vt);
    k_attn<<<dim3(NL / 32, NB), 512, 0, stream>>>(Qh, Kh, Vt, out);
}

// Round 6
// 1026.360 us; speedup vs baseline: 1.1425x; 1.1425x over previous
//
#include <hip/hip_runtime.h>

// ---------------------------------------------------------------------------
// AttentionLayer: q=XWq+bq, k=XWk+bk, v=XWv+bv; S=qk^T (NO 1/sqrt(d) scale);
// P=softmax(S); out=PV.   B=4, L=4096, D=768, fp32 in/out.
//
// Precision: hi/lo f16 split (Markidis) for X,W in PROJECTION GEMMs; Q,K,V
// hi-only f16 in attention (absmax ~0.043, budget 0.114). P f16.
//
// R6 k_attn restructure (R5 post-mortem: Sbuf partial-reduce tax + Q re-reads):
//  - waves partition KV-COLS for QK^T: full-d S[32][16]/wave, KVBLK=64.
//    No Sbuf, cross-wave comm = per-row scalar max/sum (double-buffered).
//  - Q staged in LDS once (48 KB): Q leaves the L2 stream. Traffic
//    9.44 -> 6.29 GB total (K96+V96 KB per 64-kv block-iter).
//  - (m,l) softmax state register-replicated per lane (row map of S-frags
//    == O-frags), alpha computed locally; no state LDS, no wave-0 serial.
//  - 2 barriers per 64 kv (was 2 per 32).  4 waves, 256 thr, 2 blocks/CU.
// ---------------------------------------------------------------------------

typedef _Float16 f16;
typedef _Float16 f16x8 __attribute__((ext_vector_type(8)));
typedef _Float16 f16x4 __attribute__((ext_vector_type(4)));
typedef float f32x4 __attribute__((ext_vector_type(4)));

#define NB 4
#define NL 4096
#define ND 768
#define NM (NB * NL)  // 16384 rows

__device__ __forceinline__ void split_f16(float v, f16& h, f16& l) {
    h = (f16)v;
    l = (f16)(v - (float)h);
}

// ---- convert hidden_states -> Xh, Xl (hi/lo f16), same [M][D] layout ------
__global__ __launch_bounds__(256) void k_convert_x(
    const float* __restrict__ x, f16* __restrict__ xh, f16* __restrict__ xl) {
    int i = blockIdx.x * 256 + threadIdx.x;       // group of 4 elems
    float4 v = ((const float4*)x)[i];
    float vv[4] = {v.x, v.y, v.z, v.w};
    f16x4 hv, lv;
    for (int j = 0; j < 4; ++j) {
        f16 h, l; split_f16(vv[j], h, l);
        hv[j] = h; lv[j] = l;
    }
    ((f16x4*)xh)[i] = hv;
    ((f16x4*)xl)[i] = lv;
}

// ---- transpose W [k][n] -> Wt [n][k] as hi/lo f16 (3 matrices, z picks) ---
__global__ __launch_bounds__(256) void k_convert_w(
    const float* __restrict__ Wq, const float* __restrict__ Wk,
    const float* __restrict__ Wv, f16* __restrict__ wth, f16* __restrict__ wtl) {
    __shared__ float tile[32][33];
    const float* W = blockIdx.z == 0 ? Wq : (blockIdx.z == 1 ? Wk : Wv);
    f16* th = wth + blockIdx.z * ND * ND;
    f16* tl = wtl + blockIdx.z * ND * ND;
    const int k0 = blockIdx.x * 32, n0 = blockIdx.y * 32;
    const int tx = threadIdx.x & 31, ty = threadIdx.x >> 5;  // ty 0..7
    for (int r = 0; r < 4; ++r)
        tile[r * 8 + ty][tx] = W[(k0 + r * 8 + ty) * ND + n0 + tx];
    __syncthreads();
    for (int r = 0; r < 4; ++r) {
        float v = tile[tx][r * 8 + ty];
        int n = n0 + r * 8 + ty, k = k0 + tx;
        f16 h, l; split_f16(v, h, l);
        th[n * ND + k] = h;
        tl[n * ND + k] = l;
    }
}

// ---- projection GEMM: C[M,N] = X[M,K] * W[K,N] + bias, hi/lo MFMA ---------
// z=0 -> Qh (hi only), z=1 -> Kh (hi only), z=2 -> Vt ([b][d][pos], hi)
// 128x128 tile, 4 waves in 2x2, each wave 64x64 = 4x4 frags of 16x16.
__global__ __launch_bounds__(256, 2) void k_proj(
    const f16* __restrict__ xh, const f16* __restrict__ xl,
    const f16* __restrict__ wth, const f16* __restrict__ wtl,
    const float* __restrict__ bq, const float* __restrict__ bk,
    const float* __restrict__ bv,
    f16* __restrict__ qh, f16* __restrict__ kh, f16* __restrict__ vt) {
    const int z = blockIdx.z;
    const f16* wh = wth + z * ND * ND;
    const f16* wl = wtl + z * ND * ND;
    const float* bias = z == 0 ? bq : (z == 1 ? bk : bv);
    const int m0 = blockIdx.x * 128, n0 = blockIdx.y * 128;

    // LDS: rows padded to 40 f16 (80B stride -> only 2-way bank aliasing=free)
    __shared__ f16 Ah[128 * 40], Al[128 * 40], Bh[128 * 40], Bl[128 * 40];

    const int t = threadIdx.x;
    const int lane = t & 63, quad = lane >> 4, l16 = lane & 15;
    const int wave = t >> 6, wm = wave >> 1, wn = wave & 1;

    f32x4 acc[4][4] = {};

    for (int kt = 0; kt < 24; ++kt) {
        const int k0 = kt * 32;
        __syncthreads();
        // stage 128x32 tiles (hi+lo of A and B) via 16B chunks
        for (int i = 0; i < 2; ++i) {
            int c = i * 256 + t;
            int row = c >> 2, kc = (c & 3) * 8;
            *(uint4*)&Ah[row * 40 + kc] = *(const uint4*)&xh[(m0 + row) * ND + k0 + kc];
            *(uint4*)&Al[row * 40 + kc] = *(const uint4*)&xl[(m0 + row) * ND + k0 + kc];
            *(uint4*)&Bh[row * 40 + kc] = *(const uint4*)&wh[(n0 + row) * ND + k0 + kc];
            *(uint4*)&Bl[row * 40 + kc] = *(const uint4*)&wl[(n0 + row) * ND + k0 + kc];
        }
        __syncthreads();
        f16x8 ah[4], al[4], bh[4], bl[4];
#pragma unroll
        for (int f = 0; f < 4; ++f) {
            int m = wm * 64 + f * 16 + l16;
            ah[f] = *(const f16x8*)&Ah[m * 40 + quad * 8];
            al[f] = *(const f16x8*)&Al[m * 40 + quad * 8];
            int n = wn * 64 + f * 16 + l16;
            bh[f] = *(const f16x8*)&Bh[n * 40 + quad * 8];
            bl[f] = *(const f16x8*)&Bl[n * 40 + quad * 8];
        }
#pragma unroll
        for (int fm = 0; fm < 4; ++fm)
#pragma unroll
            for (int fn = 0; fn < 4; ++fn) {
                f32x4 c = acc[fm][fn];
                c = __builtin_amdgcn_mfma_f32_16x16x32_f16(al[fm], bh[fn], c, 0, 0, 0);
                c = __builtin_amdgcn_mfma_f32_16x16x32_f16(ah[fm], bl[fn], c, 0, 0, 0);
                c = __builtin_amdgcn_mfma_f32_16x16x32_f16(ah[fm], bh[fn], c, 0, 0, 0);
                acc[fm][fn] = c;
            }
    }
    // epilogue: C/D layout col=lane&15, row=quad*4+reg  [verified m89/m91]
#pragma unroll
    for (int fm = 0; fm < 4; ++fm)
#pragma unroll
        for (int fn = 0; fn < 4; ++fn) {
            int col = n0 + wn * 64 + fn * 16 + l16;
            float bv_ = bias[col];
#pragma unroll
            for (int r = 0; r < 4; ++r) {
                int row = m0 + wm * 64 + fm * 16 + quad * 4 + r;
                float v = acc[fm][fn][r] + bv_;
                f16 h = (f16)v;
                if (z == 0) { qh[row * ND + col] = h; }
                else if (z == 1) { kh[row * ND + col] = h; }
                else {
                    int b = row >> 12, pos = row & 4095;
                    vt[(b * ND + col) * NL + pos] = h;  // V^T for PV b_frags
                }
            }
        }
}

// ---- flash attention: QT=32, KVBLK=64, 4 waves (256 thr), 2 blocks/CU ----
// QK^T: wave w computes FULL-d S[32 q][16 kv] for kv-cols [w*16, w*16+16)
//   (24 k-steps over 768). Cross-wave comm: per-row scalar max/sum only,
//   double-buffered (mwT/psT[kt&1]) -> 2 barriers per tile, race-free.
// Softmax state (m,l) register-replicated per lane: S-frag rows ==
//   O-frag rows (fm*16+quad*4+r), so alpha/l are computed locally.
// PV: wave w owns 192 output cols; P via Pbuf; V streamed per-fn.
__global__ __launch_bounds__(256, 2) void k_attn(
    const f16* __restrict__ qh, const f16* __restrict__ kh,
    const f16* __restrict__ vt, float* __restrict__ out) {
    const int qt = blockIdx.x, b = blockIdx.y;
    const int q0 = qt * 32;
    const int t = threadIdx.x, w = t >> 6, lane = t & 63;
    const int quad = lane >> 4, l16 = lane & 15;
    const int dw = w * 192;   // PV output col chunk
    const int kvw = w * 16;   // QK^T kv-col slice

    __shared__ f16 Qbuf[32 * 776];     // Q hi staged once; stride 776 (pad 8)
    __shared__ f16 Pbuf[32 * 72];      // P tile [32][64+8]
    __shared__ float mwT[2][32][4];    // per-wave partial rowmax (ping-pong)
    __shared__ float psT[2][32][4];    // per-wave partial rowsum (ping-pong)

    // stage Q[32][768] hi into LDS (read-only afterwards)
    for (int c = t; c < 3072; c += 256) {
        int row = c / 96, col8 = (c % 96) * 8;
        *(uint4*)&Qbuf[row * 776 + col8] =
            *(const uint4*)&qh[(b * NL + q0 + row) * ND + col8];
    }
    // register-replicated softmax state for rows fm*16 + quad*4 + r
    float mreg[2][4], lreg[2][4];
#pragma unroll
    for (int fm = 0; fm < 2; ++fm)
#pragma unroll
        for (int r = 0; r < 4; ++r) { mreg[fm][r] = -1e30f; lreg[fm][r] = 0.f; }
    f32x4 oacc[2][12] = {};
    __syncthreads();

    for (int kt = 0; kt < 64; ++kt) {
        const int p0 = kt * 64;
        const int cb = kt & 1;

        // ---- S[32][16] = Q[32][768] x K^T[768][16] (this wave's kv slice) --
        f32x4 sacc[2] = {};
#pragma unroll
        for (int ks = 0; ks < 24; ++ks) {
            const int d = ks * 32 + quad * 8;
            f16x8 bH = *(const f16x8*)&kh[(b * NL + p0 + kvw + l16) * ND + d];
            f16x8 a0 = *(const f16x8*)&Qbuf[l16 * 776 + d];
            f16x8 a1 = *(const f16x8*)&Qbuf[(16 + l16) * 776 + d];
            sacc[0] = __builtin_amdgcn_mfma_f32_16x16x32_f16(a0, bH, sacc[0], 0, 0, 0);
            sacc[1] = __builtin_amdgcn_mfma_f32_16x16x32_f16(a1, bH, sacc[1], 0, 0, 0);
        }

        // ---- per-wave partial rowmax over the 16 l16-lanes ----
        float pm[2][4];
#pragma unroll
        for (int fm = 0; fm < 2; ++fm)
#pragma unroll
            for (int r = 0; r < 4; ++r) {
                float v = sacc[fm][r];
#pragma unroll
                for (int off = 1; off < 16; off <<= 1) v = fmaxf(v, __shfl_xor(v, off, 64));
                pm[fm][r] = v;
            }
        if (l16 == 0) {
#pragma unroll
            for (int fm = 0; fm < 2; ++fm)
#pragma unroll
                for (int r = 0; r < 4; ++r)
                    mwT[cb][fm * 16 + quad * 4 + r][w] = pm[fm][r];
        }
        __syncthreads();  // bar1: mwT complete

        // ---- softmax: m_new (identical across waves), P, partial sums ----
        float alpha[2][4];
#pragma unroll
        for (int fm = 0; fm < 2; ++fm)
#pragma unroll
            for (int r = 0; r < 4; ++r) {
                const int row = fm * 16 + quad * 4 + r;
                f32x4 mw4 = *(const f32x4*)&mwT[cb][row][0];  // broadcast read
                float tmax = fmaxf(fmaxf(mw4[0], mw4[1]), fmaxf(mw4[2], mw4[3]));
                float m_new = fmaxf(mreg[fm][r], tmax);
                alpha[fm][r] = __expf(mreg[fm][r] - m_new);
                mreg[fm][r] = m_new;
                float p = __expf(sacc[fm][r] - m_new);
                sacc[fm][r] = p;  // reuse as P
                Pbuf[row * 72 + kvw + l16] = (f16)p;
            }
        // partial row-sums over this wave's 16 cols
#pragma unroll
        for (int fm = 0; fm < 2; ++fm)
#pragma unroll
            for (int r = 0; r < 4; ++r) {
                float v = sacc[fm][r];
#pragma unroll
                for (int off = 1; off < 16; off <<= 1) v += __shfl_xor(v, off, 64);
                if (l16 == 0) psT[cb][fm * 16 + quad * 4 + r][w] = v;
            }
        __syncthreads();  // bar2: Pbuf + psT complete

        // ---- l update (local), O rescale, PV over this wave's 192 cols ----
#pragma unroll
        for (int fm = 0; fm < 2; ++fm)
#pragma unroll
            for (int r = 0; r < 4; ++r) {
                const int row = fm * 16 + quad * 4 + r;
                f32x4 ps4 = *(const f32x4*)&psT[cb][row][0];
                lreg[fm][r] = alpha[fm][r] * lreg[fm][r] +
                              (ps4[0] + ps4[1]) + (ps4[2] + ps4[3]);
            }
#pragma unroll
        for (int fm = 0; fm < 2; ++fm)
#pragma unroll
            for (int fn = 0; fn < 12; ++fn)
#pragma unroll
                for (int r = 0; r < 4; ++r) oacc[fm][fn][r] *= alpha[fm][r];

        f16x8 pa[2][2];  // [fm][kslice of 32]
#pragma unroll
        for (int fm = 0; fm < 2; ++fm)
#pragma unroll
            for (int ks = 0; ks < 2; ++ks)
                pa[fm][ks] = *(const f16x8*)&Pbuf[(fm * 16 + l16) * 72 + ks * 32 + quad * 8];
#pragma unroll
        for (int fn = 0; fn < 12; ++fn) {
            const int dcol = dw + fn * 16 + l16;
#pragma unroll
            for (int ks = 0; ks < 2; ++ks) {
                f16x8 vb = *(const f16x8*)&vt[(b * ND + dcol) * NL + p0 + ks * 32 + quad * 8];
#pragma unroll
                for (int fm = 0; fm < 2; ++fm)
                    oacc[fm][fn] = __builtin_amdgcn_mfma_f32_16x16x32_f16(
                        pa[fm][ks], vb, oacc[fm][fn], 0, 0, 0);
            }
        }
        // no 3rd barrier: Pbuf/mwT/psT rewrites for kt+1 are ordered by
        // bar1(kt+1) / ping-pong double-buffering (see header proof).
    }

    // ---- epilogue: out = O / l (all state in registers) ----
#pragma unroll
    for (int fm = 0; fm < 2; ++fm)
#pragma unroll
        for (int fn = 0; fn < 12; ++fn) {
            int col = dw + fn * 16 + l16;
#pragma unroll
            for (int r = 0; r < 4; ++r) {
                int row = b * NL + q0 + fm * 16 + quad * 4 + r;
                out[row * ND + col] = oacc[fm][fn][r] / lreg[fm][r];
            }
        }
}

extern "C" void kernel_launch(void* const* d_in, const int* in_sizes, int n_in,
                              void* d_out, int out_size, void* d_ws, size_t ws_size,
                              hipStream_t stream) {
    const float* hs = (const float*)d_in[0];
    const float* Wq = (const float*)d_in[1];
    const float* bq = (const float*)d_in[2];
    const float* Wk = (const float*)d_in[3];
    const float* bk = (const float*)d_in[4];
    const float* Wv = (const float*)d_in[5];
    const float* bv = (const float*)d_in[6];
    float* out = (float*)d_out;

    char* ws = (char*)d_ws;
    size_t off = 0;
    auto alloc = [&](size_t bytes) {
        void* p = ws + off;
        off += (bytes + 255) & ~(size_t)255;
        return p;
    };
    const size_t MD = (size_t)NM * ND;  // 12,582,912
    f16* Xh = (f16*)alloc(MD * 2);
    f16* Xl = (f16*)alloc(MD * 2);
    f16* Wth = (f16*)alloc((size_t)3 * ND * ND * 2);
    f16* Wtl = (f16*)alloc((size_t)3 * ND * ND * 2);
    f16* Qh = (f16*)alloc(MD * 2);
    f16* Kh = (f16*)alloc(MD * 2);
    f16* Vt = (f16*)alloc(MD * 2);
    (void)ws_size; (void)in_sizes; (void)n_in; (void)out_size;

    k_convert_x<<<dim3(MD / 1024), 256, 0, stream>>>(hs, Xh, Xl);
    k_convert_w<<<dim3(24, 24, 3), 256, 0, stream>>>(Wq, Wk, Wv, Wth, Wtl);
    k_proj<<<dim3(NM / 128, ND / 128, 3), 256, 0, stream>>>(
        Xh, Xl, Wth, Wtl, bq, bk, bv, Qh, Kh, Vt);
    k_attn<<<dim3(NL / 32, NB), 256, 0, stream>>>(Qh, Kh, Vt, out);
}

// Round 7
// 831.325 us; speedup vs baseline: 1.4106x; 1.2346x over previous
//
#include <hip/hip_runtime.h>

// ---------------------------------------------------------------------------
// AttentionLayer: q=XWq+bq, k=XWk+bk, v=XWv+bv; S=qk^T (NO 1/sqrt(d) scale);
// P=softmax(S); out=PV.   B=4, L=4096, D=768, fp32 in/out.
//
// Precision: hi/lo f16 split (Markidis) for X,W in PROJECTION GEMMs; Q,K,V
// hi-only f16 in attention (absmax ~0.043, budget 0.114). P f16.
//
// R7: per-CU K/V L1-miss throughput is MSHR-capped at ~13 B/cy/CU (constant
// across R4/R5/R6 configs) -> only per-CU traffic reduction helps.
//  - QT=64, 512 thr (8 waves), grid 256 = 1 block/CU: K+V read ONCE per
//    64 q-rows per CU (was twice) -> total L2-side traffic 6.29 -> 3.15 GB.
//  - KVBLK=128 (8 waves x 16 kv-slices), 32 iterations, 2 barriers each.
//  - Q[64][768] staged once in LDS (99 KB; total LDS ~123 KB, 1 block/CU).
//  - (m,l) register-replicated (S/O frag rows coincide, fm 0..3).
//  - mwT/psT single-buffered: writes for kt+1 happen after bar1(kt+1)/
//    post-QK^T, which happens-after ALL waves passed bar2(kt), which is
//    after all reads of kt's values. Race-free with 2 barriers.
//  - rolling V prefetch (ks-slice dbuf, compile-time indexed) + ks0 slice
//    hoisted before QK^T: PV exposes no V latency at 1 block/CU.
//  - NO XCD swizzle (R3 lesson: natural dispatch keeps cross-CU lockstep).
// ---------------------------------------------------------------------------

typedef _Float16 f16;
typedef _Float16 f16x8 __attribute__((ext_vector_type(8)));
typedef _Float16 f16x4 __attribute__((ext_vector_type(4)));
typedef float f32x4 __attribute__((ext_vector_type(4)));

#define NB 4
#define NL 4096
#define ND 768
#define NM (NB * NL)  // 16384 rows

__device__ __forceinline__ void split_f16(float v, f16& h, f16& l) {
    h = (f16)v;
    l = (f16)(v - (float)h);
}

// ---- convert hidden_states -> Xh, Xl (hi/lo f16), same [M][D] layout ------
__global__ __launch_bounds__(256) void k_convert_x(
    const float* __restrict__ x, f16* __restrict__ xh, f16* __restrict__ xl) {
    int i = blockIdx.x * 256 + threadIdx.x;       // group of 4 elems
    float4 v = ((const float4*)x)[i];
    float vv[4] = {v.x, v.y, v.z, v.w};
    f16x4 hv, lv;
    for (int j = 0; j < 4; ++j) {
        f16 h, l; split_f16(vv[j], h, l);
        hv[j] = h; lv[j] = l;
    }
    ((f16x4*)xh)[i] = hv;
    ((f16x4*)xl)[i] = lv;
}

// ---- transpose W [k][n] -> Wt [n][k] as hi/lo f16 (3 matrices, z picks) ---
__global__ __launch_bounds__(256) void k_convert_w(
    const float* __restrict__ Wq, const float* __restrict__ Wk,
    const float* __restrict__ Wv, f16* __restrict__ wth, f16* __restrict__ wtl) {
    __shared__ float tile[32][33];
    const float* W = blockIdx.z == 0 ? Wq : (blockIdx.z == 1 ? Wk : Wv);
    f16* th = wth + blockIdx.z * ND * ND;
    f16* tl = wtl + blockIdx.z * ND * ND;
    const int k0 = blockIdx.x * 32, n0 = blockIdx.y * 32;
    const int tx = threadIdx.x & 31, ty = threadIdx.x >> 5;  // ty 0..7
    for (int r = 0; r < 4; ++r)
        tile[r * 8 + ty][tx] = W[(k0 + r * 8 + ty) * ND + n0 + tx];
    __syncthreads();
    for (int r = 0; r < 4; ++r) {
        float v = tile[tx][r * 8 + ty];
        int n = n0 + r * 8 + ty, k = k0 + tx;
        f16 h, l; split_f16(v, h, l);
        th[n * ND + k] = h;
        tl[n * ND + k] = l;
    }
}

// ---- projection GEMM: C[M,N] = X[M,K] * W[K,N] + bias, hi/lo MFMA ---------
// z=0 -> Qh (hi only), z=1 -> Kh (hi only), z=2 -> Vt ([b][d][pos], hi)
// 128x128 tile, 4 waves in 2x2, each wave 64x64 = 4x4 frags of 16x16.
__global__ __launch_bounds__(256, 2) void k_proj(
    const f16* __restrict__ xh, const f16* __restrict__ xl,
    const f16* __restrict__ wth, const f16* __restrict__ wtl,
    const float* __restrict__ bq, const float* __restrict__ bk,
    const float* __restrict__ bv,
    f16* __restrict__ qh, f16* __restrict__ kh, f16* __restrict__ vt) {
    const int z = blockIdx.z;
    const f16* wh = wth + z * ND * ND;
    const f16* wl = wtl + z * ND * ND;
    const float* bias = z == 0 ? bq : (z == 1 ? bk : bv);
    const int m0 = blockIdx.x * 128, n0 = blockIdx.y * 128;

    // LDS: rows padded to 40 f16 (80B stride -> only 2-way bank aliasing=free)
    __shared__ f16 Ah[128 * 40], Al[128 * 40], Bh[128 * 40], Bl[128 * 40];

    const int t = threadIdx.x;
    const int lane = t & 63, quad = lane >> 4, l16 = lane & 15;
    const int wave = t >> 6, wm = wave >> 1, wn = wave & 1;

    f32x4 acc[4][4] = {};

    for (int kt = 0; kt < 24; ++kt) {
        const int k0 = kt * 32;
        __syncthreads();
        // stage 128x32 tiles (hi+lo of A and B) via 16B chunks
        for (int i = 0; i < 2; ++i) {
            int c = i * 256 + t;
            int row = c >> 2, kc = (c & 3) * 8;
            *(uint4*)&Ah[row * 40 + kc] = *(const uint4*)&xh[(m0 + row) * ND + k0 + kc];
            *(uint4*)&Al[row * 40 + kc] = *(const uint4*)&xl[(m0 + row) * ND + k0 + kc];
            *(uint4*)&Bh[row * 40 + kc] = *(const uint4*)&wh[(n0 + row) * ND + k0 + kc];
            *(uint4*)&Bl[row * 40 + kc] = *(const uint4*)&wl[(n0 + row) * ND + k0 + kc];
        }
        __syncthreads();
        f16x8 ah[4], al[4], bh[4], bl[4];
#pragma unroll
        for (int f = 0; f < 4; ++f) {
            int m = wm * 64 + f * 16 + l16;
            ah[f] = *(const f16x8*)&Ah[m * 40 + quad * 8];
            al[f] = *(const f16x8*)&Al[m * 40 + quad * 8];
            int n = wn * 64 + f * 16 + l16;
            bh[f] = *(const f16x8*)&Bh[n * 40 + quad * 8];
            bl[f] = *(const f16x8*)&Bl[n * 40 + quad * 8];
        }
#pragma unroll
        for (int fm = 0; fm < 4; ++fm)
#pragma unroll
            for (int fn = 0; fn < 4; ++fn) {
                f32x4 c = acc[fm][fn];
                c = __builtin_amdgcn_mfma_f32_16x16x32_f16(al[fm], bh[fn], c, 0, 0, 0);
                c = __builtin_amdgcn_mfma_f32_16x16x32_f16(ah[fm], bl[fn], c, 0, 0, 0);
                c = __builtin_amdgcn_mfma_f32_16x16x32_f16(ah[fm], bh[fn], c, 0, 0, 0);
                acc[fm][fn] = c;
            }
    }
    // epilogue: C/D layout col=lane&15, row=quad*4+reg  [verified m89/m91]
#pragma unroll
    for (int fm = 0; fm < 4; ++fm)
#pragma unroll
        for (int fn = 0; fn < 4; ++fn) {
            int col = n0 + wn * 64 + fn * 16 + l16;
            float bv_ = bias[col];
#pragma unroll
            for (int r = 0; r < 4; ++r) {
                int row = m0 + wm * 64 + fm * 16 + quad * 4 + r;
                float v = acc[fm][fn][r] + bv_;
                f16 h = (f16)v;
                if (z == 0) { qh[row * ND + col] = h; }
                else if (z == 1) { kh[row * ND + col] = h; }
                else {
                    int b = row >> 12, pos = row & 4095;
                    vt[(b * ND + col) * NL + pos] = h;  // V^T for PV b_frags
                }
            }
        }
}

// ---- flash attention: QT=64, KVBLK=128, 8 waves (512 thr), 1 block/CU ----
// QK^T: wave w computes FULL-d S[64 q][16 kv] for kv-cols [w*16, +16)
//   (24 k-steps over 768), Q from LDS. Cross-wave comm: per-row scalar
//   max/sum via mwT/psT (single-buffered; race-freedom proof in header).
// PV: wave w owns 96 output cols (dw=w*96); P via Pbuf; V rolling-prefetch.
__global__ __launch_bounds__(512, 2) void k_attn(
    const f16* __restrict__ qh, const f16* __restrict__ kh,
    const f16* __restrict__ vt, float* __restrict__ out) {
    const int qt = blockIdx.x, b = blockIdx.y;
    const int q0 = qt * 64;
    const int t = threadIdx.x, w = t >> 6, lane = t & 63;
    const int quad = lane >> 4, l16 = lane & 15;
    const int dw = w * 96;    // PV output col chunk
    const int kvw = w * 16;   // QK^T kv-col slice within 128

    __shared__ f16 Qbuf[64 * 776];    // Q staged once; stride 776 (16B pad)
    __shared__ f16 Pbuf[64 * 136];    // P tile [64][128+8]
    __shared__ float mwT[64][12];     // per-wave partial rowmax (use [0..7])
    __shared__ float psT[64][12];     // per-wave partial rowsum (use [0..7])

    // stage Q[64][768] into LDS (read-only afterwards)
    for (int c = t; c < 6144; c += 512) {
        int row = c / 96, col8 = (c % 96) * 8;
        *(uint4*)&Qbuf[row * 776 + col8] =
            *(const uint4*)&qh[(b * NL + q0 + row) * ND + col8];
    }
    // register-replicated softmax state for rows fm*16 + quad*4 + r
    float mreg[4][4], lreg[4][4];
#pragma unroll
    for (int fm = 0; fm < 4; ++fm)
#pragma unroll
        for (int r = 0; r < 4; ++r) { mreg[fm][r] = -1e30f; lreg[fm][r] = 0.f; }
    f32x4 oacc[4][6] = {};
    __syncthreads();

    for (int kt = 0; kt < 32; ++kt) {
        const int p0 = kt * 128;

        // ---- prefetch V ks-slice 0 (latency hides under QK^T) ----
        f16x8 vb[2][6];
#pragma unroll
        for (int fn = 0; fn < 6; ++fn)
            vb[0][fn] = *(const f16x8*)&vt[(b * ND + dw + fn * 16 + l16) * NL +
                                           p0 + quad * 8];

        // ---- S[64][16] = Q[64][768] x K^T[768][16] (this wave's kv slice) --
        f32x4 sacc[4] = {};
#pragma unroll
        for (int ks = 0; ks < 24; ++ks) {
            const int d = ks * 32 + quad * 8;
            f16x8 bH = *(const f16x8*)&kh[(b * NL + p0 + kvw + l16) * ND + d];
#pragma unroll
            for (int fm = 0; fm < 4; ++fm) {
                f16x8 aH = *(const f16x8*)&Qbuf[(fm * 16 + l16) * 776 + d];
                sacc[fm] = __builtin_amdgcn_mfma_f32_16x16x32_f16(aH, bH, sacc[fm], 0, 0, 0);
            }
        }

        // ---- per-wave partial rowmax over the 16 l16-lanes ----
#pragma unroll
        for (int fm = 0; fm < 4; ++fm)
#pragma unroll
            for (int r = 0; r < 4; ++r) {
                float v = sacc[fm][r];
#pragma unroll
                for (int off = 1; off < 16; off <<= 1) v = fmaxf(v, __shfl_xor(v, off, 64));
                if (l16 == 0) mwT[fm * 16 + quad * 4 + r][w] = v;
            }
        __syncthreads();  // bar1: mwT complete

        // ---- softmax: m_new identical across waves; P + partial sums ----
        float alpha[4][4];
#pragma unroll
        for (int fm = 0; fm < 4; ++fm)
#pragma unroll
            for (int r = 0; r < 4; ++r) {
                const int row = fm * 16 + quad * 4 + r;
                f32x4 a4 = *(const f32x4*)&mwT[row][0];
                f32x4 b4 = *(const f32x4*)&mwT[row][4];
                float tmax = fmaxf(fmaxf(fmaxf(a4[0], a4[1]), fmaxf(a4[2], a4[3])),
                                   fmaxf(fmaxf(b4[0], b4[1]), fmaxf(b4[2], b4[3])));
                float m_new = fmaxf(mreg[fm][r], tmax);
                alpha[fm][r] = __expf(mreg[fm][r] - m_new);
                mreg[fm][r] = m_new;
                float p = __expf(sacc[fm][r] - m_new);
                Pbuf[row * 136 + kvw + l16] = (f16)p;
#pragma unroll
                for (int off = 1; off < 16; off <<= 1) p += __shfl_xor(p, off, 64);
                if (l16 == 0) psT[row][w] = p;
            }
        __syncthreads();  // bar2: Pbuf + psT complete

        // ---- l update (local), O rescale ----
#pragma unroll
        for (int fm = 0; fm < 4; ++fm)
#pragma unroll
            for (int r = 0; r < 4; ++r) {
                const int row = fm * 16 + quad * 4 + r;
                f32x4 a4 = *(const f32x4*)&psT[row][0];
                f32x4 b4 = *(const f32x4*)&psT[row][4];
                lreg[fm][r] = alpha[fm][r] * lreg[fm][r] +
                              ((a4[0] + a4[1]) + (a4[2] + a4[3])) +
                              ((b4[0] + b4[1]) + (b4[2] + b4[3]));
#pragma unroll
                for (int fn = 0; fn < 6; ++fn) oacc[fm][fn][r] *= alpha[fm][r];
            }

        // ---- PV over this wave's 96 cols, rolling V prefetch per ks ----
#pragma unroll
        for (int ks = 0; ks < 4; ++ks) {
            if (ks < 3) {
#pragma unroll
                for (int fn = 0; fn < 6; ++fn)
                    vb[(ks + 1) & 1][fn] =
                        *(const f16x8*)&vt[(b * ND + dw + fn * 16 + l16) * NL +
                                           p0 + (ks + 1) * 32 + quad * 8];
            }
            f16x8 pa[4];
#pragma unroll
            for (int fm = 0; fm < 4; ++fm)
                pa[fm] = *(const f16x8*)&Pbuf[(fm * 16 + l16) * 136 + ks * 32 + quad * 8];
#pragma unroll
            for (int fn = 0; fn < 6; ++fn)
#pragma unroll
                for (int fm = 0; fm < 4; ++fm)
                    oacc[fm][fn] = __builtin_amdgcn_mfma_f32_16x16x32_f16(
                        pa[fm], vb[ks & 1][fn], oacc[fm][fn], 0, 0, 0);
        }
        // no 3rd barrier: kt+1's mwT/psT/Pbuf writes occur after bar1(kt+1)
        // (or post-QK^T), which happens-after all waves passed bar2(kt),
        // which is after all reads of kt's values. Race-free.
    }

    // ---- epilogue: out = O / l (all state in registers) ----
#pragma unroll
    for (int fm = 0; fm < 4; ++fm)
#pragma unroll
        for (int fn = 0; fn < 6; ++fn) {
            int col = dw + fn * 16 + l16;
#pragma unroll
            for (int r = 0; r < 4; ++r) {
                int row = b * NL + q0 + fm * 16 + quad * 4 + r;
                out[row * ND + col] = oacc[fm][fn][r] / lreg[fm][r];
            }
        }
}

extern "C" void kernel_launch(void* const* d_in, const int* in_sizes, int n_in,
                              void* d_out, int out_size, void* d_ws, size_t ws_size,
                              hipStream_t stream) {
    const float* hs = (const float*)d_in[0];
    const float* Wq = (const float*)d_in[1];
    const float* bq = (const float*)d_in[2];
    const float* Wk = (const float*)d_in[3];
    const float* bk = (const float*)d_in[4];
    const float* Wv = (const float*)d_in[5];
    const float* bv = (const float*)d_in[6];
    float* out = (float*)d_out;

    char* ws = (char*)d_ws;
    size_t off = 0;
    auto alloc = [&](size_t bytes) {
        void* p = ws + off;
        off += (bytes + 255) & ~(size_t)255;
        return p;
    };
    const size_t MD = (size_t)NM * ND;  // 12,582,912
    f16* Xh = (f16*)alloc(MD * 2);
    f16* Xl = (f16*)alloc(MD * 2);
    f16* Wth = (f16*)alloc((size_t)3 * ND * ND * 2);
    f16* Wtl = (f16*)alloc((size_t)3 * ND * ND * 2);
    f16* Qh = (f16*)alloc(MD * 2);
    f16* Kh = (f16*)alloc(MD * 2);
    f16* Vt = (f16*)alloc(MD * 2);
    (void)ws_size; (void)in_sizes; (void)n_in; (void)out_size;

    k_convert_x<<<dim3(MD / 1024), 256, 0, stream>>>(hs, Xh, Xl);
    k_convert_w<<<dim3(24, 24, 3), 256, 0, stream>>>(Wq, Wk, Wv, Wth, Wtl);
    k_proj<<<dim3(NM / 128, ND / 128, 3), 256, 0, stream>>>(
        Xh, Xl, Wth, Wtl, bq, bk, bv, Qh, Kh, Vt);
    k_attn<<<dim3(NL / 64, NB), 512, 0, stream>>>(Qh, Kh, Vt, out);
}